// Round 11
// baseline (17.323 us; speedup 1.0000x reference)
//
#include <hip/hip_runtime.h>

// PairwiseRankingLoss: B=128 rows, L=1024.
// loss = sum_{b, pos i, neg j} relu(1 - s[b,i] + s[b,j]) / max(num_pairs, 1)
//
// SINGLE kernel (memset node + kernel node):
//  - grid = B*SPLIT (SPLIT=8) blocks; per-block ballot compaction into dense
//    pos[]/neg[] LDS arrays; static 18-group hot loop (R10 path, verbatim).
//  - partial sums -> 32 spread float atomic cells (128 B apart, blk&31);
//    pair counts  -> 32 spread int cells (one add per row, s==0 block).
//    No threadfence: values travel THROUGH device-coherent L2 atomics; the
//    value-add -> counter-add order is a data dependency on the returned old.
//  - completion: two-level counters (32 groups x 32 incs -> 1 x 32 incs) on
//    separate lines; last block reads the 64 cells (atomicAdd(x,0)) + writes.

#define PRL_B 128
#define PRL_L 1024
#define SPLIT 8
#define NBLK  (PRL_B * SPLIT)   // 1024 blocks
#define GSTAT 18                // static float4-groups per slice

// ws layout (128 B cells): gsum[32]@0, gpair[32]@4096, gc1[32]@8192, gc2@12288
#define WS_ZERO_BYTES 12352

// Hot loop specialized on K = pos values per thread (block-uniform runtime).
template<int K>
__device__ __forceinline__ float hotloop(const float4* __restrict__ d4,
                                         int c0, int t0, int t1, float4 pv) {
    float acc[K];
#pragma unroll
    for (int k = 0; k < K; ++k) acc[k] = 0.f;
#pragma unroll
    for (int c = 0; c < GSTAT; ++c) {
        const float4 d = d4[c0 + c];   // wave-uniform LDS broadcast, static ofs
#pragma unroll
        for (int k = 0; k < K; ++k) {
            const float pk = (k == 0) ? pv.x : (k == 1) ? pv.y : (k == 2) ? pv.z : pv.w;
            acc[k] += (fmaxf(d.x - pk, 0.f) + fmaxf(d.y - pk, 0.f))
                    + (fmaxf(d.z - pk, 0.f) + fmaxf(d.w - pk, 0.f));
        }
    }
    for (int c = t0; c < t1; ++c) {    // tail: only if nn > 4*SPLIT*GSTAT
        const float4 d = d4[c];
#pragma unroll
        for (int k = 0; k < K; ++k) {
            const float pk = (k == 0) ? pv.x : (k == 1) ? pv.y : (k == 2) ? pv.z : pv.w;
            acc[k] += (fmaxf(d.x - pk, 0.f) + fmaxf(d.y - pk, 0.f))
                    + (fmaxf(d.z - pk, 0.f) + fmaxf(d.w - pk, 0.f));
        }
    }
    float r = 0.f;
#pragma unroll
    for (int k = 0; k < K; ++k) r += acc[k];
    return r;
}

__global__ __launch_bounds__(256, 4) void prl_fused(
    const float* __restrict__ y_pred,
    const int*   __restrict__ y_true,
    float*        gsum,    // 32 cells, stride 32 floats (pre-zeroed)
    int*          gpair,   // 32 cells, stride 32 ints   (pre-zeroed)
    unsigned int* gc1,     // 32 cells, stride 32 uints  (pre-zeroed)
    unsigned int* gc2,     // 1 uint                     (pre-zeroed)
    float* __restrict__ out)
{
    __shared__ float4 s_pos4[PRL_L / 4];   // compacted pos scores (+3e38 pad)
    __shared__ float4 s_neg4[PRL_L / 4];   // compacted 1+neg scores (-3e38 pad)
    __shared__ int    s_cntP[4];
    __shared__ float  s_wsum[4];
    __shared__ int    s_last;
    float* s_pos = (float*)s_pos4;
    float* s_neg = (float*)s_neg4;

    const int blk  = blockIdx.x;
    const int b    = blk >> 3;            // / SPLIT
    const int s    = blk & (SPLIT - 1);
    const int t    = threadIdx.x;
    const int lane = t & 63;
    const int w    = t >> 6;

    // Vectorized staging: one float4 + one int4 per thread covers the row.
    const float4 sc = ((const float4*)(y_pred + (size_t)b * PRL_L))[t];
    const int4   lv = ((const int4*)  (y_true + (size_t)b * PRL_L))[t];
    const float sv[4] = {sc.x, sc.y, sc.z, sc.w};
    const int   lb[4] = {lv.x, lv.y, lv.z, lv.w};

    // Pass 1: per-wave pos masks via ballot; labels in {0,1} => neg = ~pos.
    unsigned long long mP[4];
    int cP = 0;
#pragma unroll
    for (int r = 0; r < 4; ++r) {
        mP[r] = __ballot(lb[r] == 1);
        cP += (int)__popcll(mP[r]);
    }
    if (lane == 0) s_cntP[w] = cP;

    // Sentinel-init (pad regions survive; valid regions overwritten below).
    s_pos4[t] = make_float4( 3.0e38f,  3.0e38f,  3.0e38f,  3.0e38f);
    s_neg4[t] = make_float4(-3.0e38f, -3.0e38f, -3.0e38f, -3.0e38f);
    __syncthreads();

    // Wave offsets + row totals (np; nn = L - np).
    int offP = 0, np = 0;
#pragma unroll
    for (int ww = 0; ww < 4; ++ww) {
        const int p_ = s_cntP[ww];
        np += p_;
        if (ww < w) offP += p_;
    }
    const int nn   = PRL_L - np;
    const int offN = 256 * w - offP;

    // Pass 2: scatter compacted values (order irrelevant).
    const unsigned long long lt = (1ULL << lane) - 1ULL;
    int bP = offP, bN = offN;
#pragma unroll
    for (int r = 0; r < 4; ++r) {
        const unsigned long long mp = mP[r], mn = ~mp;
        if (lb[r] == 1) s_pos[bP + (int)__popcll(mp & lt)] = sv[r];
        else            s_neg[bN + (int)__popcll(mn & lt)] = 1.0f + sv[r];
        bP += (int)__popcll(mp);
        bN += 64 - (int)__popcll(mp);
    }
    __syncthreads();

    // This thread's pos values (sentinel-padded reads are safe).
    const float4 pv = make_float4(s_pos[t], s_pos[t + 256],
                                  s_pos[t + 512], s_pos[t + 768]);
    const int KP  = (np + 255) >> 8;              // 0..4, block-uniform
    const int NN4 = (nn + 3) >> 2;                // float4 groups of negs

    // Static slice [s*GSTAT, s*GSTAT+GSTAT); sentinels past NN4 contribute 0.
    const int c0 = s * GSTAT;                     // max 144 <= 256
    int t0 = 0, t1 = 0;
    if (s == SPLIT - 1 && NN4 > SPLIT * GSTAT) {  // nn > 576: rare tail
        t0 = SPLIT * GSTAT;
        t1 = NN4;
    }

    float local;
    const float4* neg4 = (const float4*)s_neg4;
    switch (KP) {
        case 0:  local = 0.f; break;
        case 1:  local = hotloop<1>(neg4, c0, t0, t1, pv); break;
        case 2:  local = hotloop<2>(neg4, c0, t0, t1, pv); break;
        case 3:  local = hotloop<3>(neg4, c0, t0, t1, pv); break;
        default: local = hotloop<4>(neg4, c0, t0, t1, pv); break;
    }

    // Block reduction of the hinge partial.
#pragma unroll
    for (int off = 32; off >= 1; off >>= 1)
        local += __shfl_down(local, off, 64);
    if (lane == 0) s_wsum[w] = local;
    __syncthreads();

    if (t == 0) {
        const float rs = (s_wsum[0] + s_wsum[1]) + (s_wsum[2] + s_wsum[3]);
        // Spread value cells: adjacent blocks -> different 128B lines.
        const float oldv = atomicAdd(&gsum[(blk & 31) * 32], rs);
        int oldp = 0;
        if (s == 0) oldp = atomicAdd(&gpair[(b & 31) * 32], np * nn);
        // Data dependency: counter inc consumes the returned olds (never-true
        // terms, both olds are always >= 0) => value-adds complete first.
        const unsigned inc = 1u
            + ((__float_as_uint(oldv) == 0xFF7FFFFFu) ? 1u : 0u)
            + ((oldp == -2147480001) ? 1u : 0u);
        // Two-level completion counters (32 x 32 incs -> 1 x 32 incs).
        const unsigned o1 = atomicAdd(&gc1[(blk >> 5) * 32], inc);
        int last = 0;
        if (o1 == 31u) {
            const unsigned o2 = atomicAdd(gc2, 1u);
            last = (o2 == 31u);
        }
        s_last = last;
    }
    __syncthreads();

    if (s_last) {
        // All value-adds happened-before (cell -> gc1 -> gc2 dependency chain).
        // Coherent cell readback through the same L2 atomic path.
        float v = 0.f; int pp = 0;
        if (t < 32) {
            v  = atomicAdd(&gsum[t * 32], 0.0f);
            pp = atomicAdd(&gpair[t * 32], 0);
        }
#pragma unroll
        for (int off = 32; off >= 1; off >>= 1) {   // lanes >=32 carry zeros
            v  += __shfl_down(v,  off, 64);
            pp += __shfl_down(pp, off, 64);
        }
        if (t == 0)
            out[0] = (pp > 0) ? (v / fmaxf((float)pp, 1.0f)) : v;
    }
}

extern "C" void kernel_launch(void* const* d_in, const int* in_sizes, int n_in,
                              void* d_out, int out_size, void* d_ws, size_t ws_size,
                              hipStream_t stream) {
    const float* y_pred = (const float*)d_in[0];
    const int*   y_true = (const int*)d_in[1];
    float* out = (float*)d_out;

    float*        gsum  = (float*)d_ws;
    int*          gpair = (int*)((char*)d_ws + 4096);
    unsigned int* gc1   = (unsigned int*)((char*)d_ws + 8192);
    unsigned int* gc2   = (unsigned int*)((char*)d_ws + 12288);

    hipMemsetAsync(d_ws, 0, WS_ZERO_BYTES, stream);  // zero cells + counters
    prl_fused<<<NBLK, 256, 0, stream>>>(y_pred, y_true, gsum, gpair, gc1, gc2, out);
}